// Round 8
// baseline (151.553 us; speedup 1.0000x reference)
//
#include <hip/hip_runtime.h>
#include <math.h>

#define BSZ 4
#define SSZ 1024
#define EMBD 128
#define HN 4
#define DN 32
#define TQ (SSZ - 1)      // 1023 queries per batch
#define NROWS (BSZ * TQ)  // 4092

typedef __attribute__((ext_vector_type(8))) short bf16x8;
typedef __attribute__((ext_vector_type(4))) short bf16x4;
typedef __attribute__((ext_vector_type(4))) float f32x4;

static __device__ __forceinline__ unsigned short f2bf(float x) {
    union { float f; unsigned u; } v; v.f = x;
    unsigned r = v.u + 0x7fffu + ((v.u >> 16) & 1u);   // RNE
    return (unsigned short)(r >> 16);
}
static __device__ __forceinline__ bf16x8 cvt8(const float4 a, const float4 b) {
    bf16x8 v;
    v[0] = (short)f2bf(a.x); v[1] = (short)f2bf(a.y);
    v[2] = (short)f2bf(a.z); v[3] = (short)f2bf(a.w);
    v[4] = (short)f2bf(b.x); v[5] = (short)f2bf(b.y);
    v[6] = (short)f2bf(b.z); v[7] = (short)f2bf(b.w);
    return v;
}

// ---------------------------------------------------------------------------
// Kernel 1: embed + project via MFMA, double-buffered weight staging
// (1 barrier per round). Block = 16 tokens, 256 threads, wave w = head w.
// 20 rounds: r<8 Wh (A = e then a), 8..11 Wq, 12..15 Wk, 16..19 Wv (A=inter).
// ---------------------------------------------------------------------------
__global__ __launch_bounds__(256)
void embed5_kernel(const int* __restrict__ idx, const int* __restrict__ flg,
                   const float* __restrict__ item_emb, const float* __restrict__ ans_emb,
                   const float* __restrict__ Wq, const float* __restrict__ bq,
                   const float* __restrict__ Wk, const float* __restrict__ bk,
                   const float* __restrict__ Wv, const float* __restrict__ bv,
                   const float* __restrict__ Wh, const float* __restrict__ bh_bias,
                   unsigned short* __restrict__ Qts, unsigned short* __restrict__ Kts,
                   unsigned short* __restrict__ Vts,
                   float* __restrict__ ec, float* __restrict__ srw)
{
    __shared__ __align__(16) unsigned short esb[16][136];
    __shared__ __align__(16) unsigned short asb[16][136];
    __shared__ __align__(16) unsigned short intb[16][136];
    __shared__ __align__(16) unsigned short Wt[2][128][40];

    const int tid = threadIdx.x;
    const int tok0 = blockIdx.x * 16;
    const int b = blockIdx.x >> 6;
    const int s0 = tok0 & 1023;
    const int w = tid >> 6, lane = tid & 63;
    const int quad = lane >> 4, col = lane & 15;

    // ---- stage e, a (bf16) + ec (fp32) ----
    {
        const int tk = tid >> 4;
        const int d0 = (tid & 15) * 8;
        const int tok = tok0 + tk;
        const float* esrc = item_emb + (size_t)idx[tok] * EMBD + d0;
        const float* asrc = ans_emb + (size_t)flg[tok] * EMBD + d0;
        const float4 e0 = *(const float4*)esrc;
        const float4 e1 = *(const float4*)(esrc + 4);
        const float4 a0 = *(const float4*)asrc;
        const float4 a1 = *(const float4*)(asrc + 4);
        *(float4*)(ec + (size_t)tok * EMBD + d0) = e0;
        *(float4*)(ec + (size_t)tok * EMBD + d0 + 4) = e1;
        *(bf16x8*)&esb[tk][d0] = cvt8(e0, e1);
        *(bf16x8*)&asb[tk][d0] = cvt8(a0, a1);
    }

    const int jb = (tid & 31) * 4;
    const int ib = (tid >> 5) * 4;
    float rr[4][4];

    #define WSRC(R) ((R) < 8 ? Wh + (size_t)(R) * 4096                     \
                  : (R) < 12 ? Wq + (size_t)((R) - 8) * 4096               \
                  : (R) < 16 ? Wk + (size_t)((R) - 12) * 4096              \
                  : Wv + (size_t)((R) - 16) * 4096)
    #define LOADW(P)                                                       \
    {                                                                      \
        const float* _p = (P);                                             \
        *(float4*)rr[0] = *(const float4*)(_p + (ib + 0) * 128 + jb);      \
        *(float4*)rr[1] = *(const float4*)(_p + (ib + 1) * 128 + jb);      \
        *(float4*)rr[2] = *(const float4*)(_p + (ib + 2) * 128 + jb);      \
        *(float4*)rr[3] = *(const float4*)(_p + (ib + 3) * 128 + jb);      \
    }
    #define STOREW(B)                                                      \
    {                                                                      \
        _Pragma("unroll")                                                  \
        for (int jj = 0; jj < 4; jj++) {                                   \
            bf16x4 v;                                                      \
            v[0] = (short)f2bf(rr[0][jj]); v[1] = (short)f2bf(rr[1][jj]);  \
            v[2] = (short)f2bf(rr[2][jj]); v[3] = (short)f2bf(rr[3][jj]);  \
            *(bf16x4*)&Wt[B][jb + jj][ib] = v;                             \
        }                                                                  \
    }

    f32x4 accI[2] = {{0.f,0.f,0.f,0.f},{0.f,0.f,0.f,0.f}};
    f32x4 accQ[2] = {{0.f,0.f,0.f,0.f},{0.f,0.f,0.f,0.f}};
    f32x4 accK[2] = {{0.f,0.f,0.f,0.f},{0.f,0.f,0.f,0.f}};
    f32x4 accV[2] = {{0.f,0.f,0.f,0.f},{0.f,0.f,0.f,0.f}};

    LOADW(WSRC(0));
    STOREW(0);
    __syncthreads();

    #pragma unroll
    for (int r = 0; r < 20; r++) {
        if (r < 19) LOADW(WSRC(r + 1));     // prefetch (overlaps MFMA below)

        const unsigned short (*Ab)[136] = (r < 4) ? esb : (r < 8) ? asb
                                        : (r < 16) ? esb : intb;
        const int koff = ((r < 8) ? (r & 3) : (r < 12) ? (r - 8)
                        : (r < 16) ? (r - 12) : (r - 16)) * 32;
        const bf16x8 af = *(const bf16x8*)&Ab[col][koff + quad * 8];
        f32x4* acc = (r < 8) ? accI : (r < 12) ? accQ : (r < 16) ? accK : accV;
        #pragma unroll
        for (int ntl = 0; ntl < 2; ntl++) {
            const bf16x8 bf = *(const bf16x8*)&Wt[r & 1][w * 32 + ntl * 16 + col][quad * 8];
            acc[ntl] = __builtin_amdgcn_mfma_f32_16x16x32_bf16(af, bf, acc[ntl], 0, 0, 0);
        }
        if (r == 7) {   // inter complete -> intb (round-7 barrier publishes)
            #pragma unroll
            for (int ntl = 0; ntl < 2; ntl++) {
                const int j = w * 32 + ntl * 16 + col;
                const float bb = bh_bias[j];
                #pragma unroll
                for (int r4 = 0; r4 < 4; r4++)
                    intb[quad * 4 + r4][j] = f2bf(accI[ntl][r4] + bb);
            }
        }
        if (r < 19) STOREW((r + 1) & 1);    // write other buffer
        __syncthreads();
    }
    #undef LOADW
    #undef STOREW
    #undef WSRC

    // ---- epilogue: biases, sr, bf16 stores ----
    const int bhn = b * HN + w;
    const float scale = 0.17677669529663687f;
    float p[4] = {0.f, 0.f, 0.f, 0.f};
    #pragma unroll
    for (int ntl = 0; ntl < 2; ntl++) {
        const int j = w * 32 + ntl * 16 + col;
        const float bQ = bq[j], bK = bk[j], bV = bv[j];
        #pragma unroll
        for (int r = 0; r < 4; r++) {
            const float qv = accQ[ntl][r] + bQ;
            const float kv = accK[ntl][r] + bK;
            const int s = s0 + quad * 4 + r;
            const size_t o = ((size_t)bhn * SSZ + s) * DN + ntl * 16 + col;
            Qts[o] = f2bf(qv * scale);
            Kts[o] = f2bf(kv);
            Vts[o] = f2bf(accV[ntl][r] + bV);
            p[r] = fmaf(qv, kv, p[r]);
        }
    }
    #pragma unroll
    for (int r = 0; r < 4; r++) {
        float pr = p[r];
        pr += __shfl_xor(pr, 1, 64);
        pr += __shfl_xor(pr, 2, 64);
        pr += __shfl_xor(pr, 4, 64);
        pr += __shfl_xor(pr, 8, 64);
        if (col == 0)
            srw[(size_t)bhn * SSZ + s0 + quad * 4 + r] = pr * scale;
    }
}

// ---------------------------------------------------------------------------
// Kernel 2: fused scan + MFMA attention, barrier-free main loop.
// Block = (bh, qt of 64 queries). Wave w owns key chunks c = w, w+4, ... for
// ALL 64 queries, using PRIVATE LDS buffers (no cross-wave sync in loop).
// S computed transposed (A=K, B=Q) so per-lane query invariants = 4 regs.
// Merge: no-max softmax partials are pure sums -> LDS atomicAdd + 1 barrier.
// ---------------------------------------------------------------------------
__global__ __launch_bounds__(256)
void attn5_kernel(const unsigned short* __restrict__ Qts,
                  const unsigned short* __restrict__ Kts,
                  const unsigned short* __restrict__ Vts,
                  const float* __restrict__ srw, const float* __restrict__ gaps,
                  const float* __restrict__ theta_raw, float* __restrict__ csw)
{
    __shared__ __align__(16) unsigned short Kw[4][64][40];   // per-wave [key][d]
    __shared__ __align__(16) unsigned short Vw[4][32][72];   // per-wave [d][key]
    __shared__ __align__(16) unsigned short Pw[4][64][72];   // per-wave [query][key]
    __shared__ float EpS[SSZ + 1];
    __shared__ float PpS[SSZ + 2];
    __shared__ float wtot[4];
    __shared__ float mrg[64][36];                            // [query][d 0..31, l at 32]

    const int bid = blockIdx.x;        // bh*16 + qt
    const int qt = bid & 15;
    const int bh = bid >> 4;
    const int b = bh >> 2, h = bh & 3;
    const int tid = threadIdx.x;
    const int w = tid >> 6, lane = tid & 63;
    const int quad = lane >> 4, col = lane & 15;
    const int t0 = qt * 64 + 1;

    // ---- zero merge buffer ----
    for (int x = tid; x < 64 * 36; x += 256) ((float*)mrg)[x] = 0.0f;

    // ---- phase 0a: Ep scan ----
    {
        const float4 sv = *(const float4*)(srw + (size_t)bh * SSZ + tid * 4);
        const float p0 = __expf(sv.x);
        const float p1 = p0 + __expf(sv.y);
        const float p2 = p1 + __expf(sv.z);
        const float p3 = p2 + __expf(sv.w);
        float s = p3;
        #pragma unroll
        for (int d = 1; d < 64; d <<= 1) {
            const float t = __shfl_up(s, d, 64);
            if (lane >= d) s += t;
        }
        if (lane == 63) wtot[w] = s;
        __syncthreads();
        float base = s - p3;
        for (int ww = 0; ww < w; ww++) base += wtot[ww];
        EpS[tid * 4 + 1] = base + p0;
        EpS[tid * 4 + 2] = base + p1;
        EpS[tid * 4 + 3] = base + p2;
        EpS[tid * 4 + 4] = base + p3;
        if (tid == 0) EpS[0] = 0.0f;
    }
    // ---- phase 0b: Pp scan ----
    {
        const float4 gv = *(const float4*)(gaps + (size_t)b * SSZ + tid * 4);
        const float p0 = fmaxf(gv.x, 1.0f);
        const float p1 = p0 + fmaxf(gv.y, 1.0f);
        const float p2 = p1 + fmaxf(gv.z, 1.0f);
        const float p3 = p2 + fmaxf(gv.w, 1.0f);
        float s = p3;
        #pragma unroll
        for (int d = 1; d < 64; d <<= 1) {
            const float t = __shfl_up(s, d, 64);
            if (lane >= d) s += t;
        }
        __syncthreads();
        if (lane == 63) wtot[w] = s;
        __syncthreads();
        float base = s - p3;
        for (int ww = 0; ww < w; ww++) base += wtot[ww];
        PpS[tid * 4 + 1] = base + p0;
        PpS[tid * 4 + 2] = base + p1;
        PpS[tid * 4 + 3] = base + p2;
        PpS[tid * 4 + 4] = base + p3;
        if (tid == 0) PpS[0] = 0.0f;
    }
    __syncthreads();

    // ---- per-lane query invariants (query q = nt*16+col, t = t0+q) ----
    const float theta = logf(1.0f + __expf(theta_raw[h])) + 1e-4f;
    const float nth = -theta;
    float Ept[4], Ppt[4], iEp[4], tft[4];
    int qrow[4];
    #pragma unroll
    for (int nt = 0; nt < 4; nt++) {
        qrow[nt] = nt * 16 + col;
        const int t = t0 + qrow[nt];
        tft[nt] = (float)t;
        const int tc = (t <= 1023) ? t : 1023;
        Ept[nt] = EpS[tc];
        Ppt[nt] = PpS[tc];
        iEp[nt] = 1.0f / Ept[nt];
    }

    // ---- Q B-frags (bf16, pre-scaled), one per n-tile ----
    bf16x8 bq[4];
    #pragma unroll
    for (int nt = 0; nt < 4; nt++) {
        int t = t0 + nt * 16 + col; if (t > 1023) t = 1023;
        bq[nt] = *(const bf16x8*)(Qts + ((size_t)(bh * SSZ + t)) * DN + quad * 8);
    }

    f32x4 acc[4][2];
    #pragma unroll
    for (int m = 0; m < 4; m++) { acc[m][0] = {0,0,0,0}; acc[m][1] = {0,0,0,0}; }
    float lsum[4] = {0.f, 0.f, 0.f, 0.f};

    // ---- prefetch first chunk ----
    bf16x8 kpre[4], vpre[4];
    {
        const size_t o = ((size_t)(bh * SSZ + w * 64 + lane)) * DN;
        #pragma unroll
        for (int j = 0; j < 4; j++) {
            kpre[j] = *(const bf16x8*)(Kts + o + j * 8);
            vpre[j] = *(const bf16x8*)(Vts + o + j * 8);
        }
    }

    for (int c = w; c <= qt; c += 4) {
        // stage current chunk into private buffers
        #pragma unroll
        for (int j = 0; j < 4; j++) *(bf16x8*)&Kw[w][lane][j * 8] = kpre[j];
        #pragma unroll
        for (int j = 0; j < 4; j++)
            #pragma unroll
            for (int k = 0; k < 8; k++) Vw[w][j * 8 + k][lane] = (unsigned short)vpre[j][k];
        // prefetch next chunk
        if (c + 4 <= qt) {
            const size_t o = ((size_t)(bh * SSZ + (c + 4) * 64 + lane)) * DN;
            #pragma unroll
            for (int j = 0; j < 4; j++) {
                kpre[j] = *(const bf16x8*)(Kts + o + j * 8);
                vpre[j] = *(const bf16x8*)(Vts + o + j * 8);
            }
        }

        const bool full = (c < qt);
        // ---- S^T = K Q^T (per m-tile of keys), decay, P ----
        #pragma unroll
        for (int mt = 0; mt < 4; mt++) {
            const bf16x8 af = *(const bf16x8*)&Kw[w][mt * 16 + col][quad * 8];
            f32x4 raw[4];
            #pragma unroll
            for (int nt = 0; nt < 4; nt++) {
                f32x4 z = {0.f, 0.f, 0.f, 0.f};
                raw[nt] = __builtin_amdgcn_mfma_f32_16x16x32_bf16(af, bq[nt], z, 0, 0, 0);
            }
            #pragma unroll
            for (int r = 0; r < 4; r++) {
                const int kl = mt * 16 + quad * 4 + r;     // key-local
                const int i_ = c * 64 + kl;                // key-global
                const float Epi = EpS[i_];
                const float Ppi = PpS[i_];
                const float fi = (float)i_;
                #pragma unroll
                for (int nt = 0; nt < 4; nt++) {
                    const float pdv = (tft[nt] - fi) * (Ppt[nt] - Ppi)
                                    * ((Ept[nt] - Epi) * iEp[nt]);
                    const float sc = raw[nt][r] * __expf(nth * pdv);
                    float p = __expf(sc);
                    p = (full || kl <= qrow[nt]) ? p : 0.0f;
                    lsum[nt] += p;
                    Pw[w][nt * 16 + col][kl] = f2bf(p);
                }
            }
        }
        // ---- PV into persistent acc ----
        #pragma unroll
        for (int mtq = 0; mtq < 4; mtq++) {
            #pragma unroll
            for (int kc = 0; kc < 2; kc++) {
                const bf16x8 ap = *(const bf16x8*)&Pw[w][mtq * 16 + col][kc * 32 + quad * 8];
                const bf16x8 bv0 = *(const bf16x8*)&Vw[w][col][kc * 32 + quad * 8];
                const bf16x8 bv1 = *(const bf16x8*)&Vw[w][16 + col][kc * 32 + quad * 8];
                acc[mtq][0] = __builtin_amdgcn_mfma_f32_16x16x32_bf16(ap, bv0, acc[mtq][0], 0, 0, 0);
                acc[mtq][1] = __builtin_amdgcn_mfma_f32_16x16x32_bf16(ap, bv1, acc[mtq][1], 0, 0, 0);
            }
        }
    }

    // ---- merge: lsum across quads, then atomicAdd into mrg ----
    #pragma unroll
    for (int nt = 0; nt < 4; nt++) {
        float l = lsum[nt];
        l += __shfl_xor(l, 16, 64);
        l += __shfl_xor(l, 32, 64);
        if (quad == 0) atomicAdd(&mrg[nt * 16 + col][32], l);
    }
    #pragma unroll
    for (int mtq = 0; mtq < 4; mtq++)
        #pragma unroll
        for (int ntv = 0; ntv < 2; ntv++)
            #pragma unroll
            for (int r = 0; r < 4; r++)
                atomicAdd(&mrg[mtq * 16 + quad * 4 + r][ntv * 16 + col], acc[mtq][ntv][r]);
    __syncthreads();

    // ---- normalize + write csw ----
    {
        const int q = tid >> 2, dg = tid & 3;
        const int t = t0 + q;
        if (t <= 1023) {
            const float inv = 1.0f / mrg[q][32];
            float* dst = csw + ((size_t)(b * TQ + (t - 1))) * EMBD + h * DN + dg * 8;
            #pragma unroll
            for (int d = 0; d < 8; d++) dst[d] = mrg[q][dg * 8 + d] * inv;
        }
    }
}

// ---------------------------------------------------------------------------
// Kernel 3: MLP via MFMA. 16 rows/block (256 blocks). Wave w owns n-quarter w
// with wave-private W1 staging (no barrier between W1 stage and GEMM).
// ---------------------------------------------------------------------------
__global__ __launch_bounds__(256)
void mlp4_kernel(const float* __restrict__ csw, const float* __restrict__ ec,
                 const float* __restrict__ W1, const float* __restrict__ b1,
                 const float* __restrict__ W2, const float* __restrict__ b2,
                 float* __restrict__ out)
{
    __shared__ __align__(16) unsigned short featb[16][264];
    __shared__ __align__(16) unsigned short W1q[4][32][264];
    __shared__ float sred[4][16];

    const int tid = threadIdx.x;
    const int r0 = blockIdx.x * 16;
    const int w = tid >> 6, lane = tid & 63;
    const int quad = lane >> 4, col = lane & 15;

    // ---- stage feat (16 rows x 256 cols) ----
    {
        const int rr = tid >> 4;
        const int c0 = (tid & 15) * 16;
        int row = r0 + rr; if (row >= NROWS) row = NROWS - 1;
        const float* src;
        if (c0 < 128) {
            src = csw + (size_t)row * EMBD + c0;
        } else {
            const int bb = row / TQ;
            const int tt = row - bb * TQ + 1;
            src = ec + ((size_t)(bb * SSZ + tt)) * EMBD + (c0 - 128);
        }
        const float4 f0 = ((const float4*)src)[0];
        const float4 f1 = ((const float4*)src)[1];
        const float4 f2 = ((const float4*)src)[2];
        const float4 f3 = ((const float4*)src)[3];
        *(bf16x8*)&featb[rr][c0]     = cvt8(f0, f1);
        *(bf16x8*)&featb[rr][c0 + 8] = cvt8(f2, f3);
    }

    // ---- wave-private W1 quarter staging: cols [w*32, w*32+32) ----
    {
        const int jl = (lane & 7) * 4;          // local col group
        const int ib2 = (lane >> 3) * 4;        // k rows base
        const int jg = w * 32 + jl;             // global col
        for (int ic = 0; ic < 8; ic++) {
            const int i0 = ic * 32 + ib2;
            float rr[4][4];
            *(float4*)rr[0] = *(const float4*)(W1 + (size_t)(i0 + 0) * 128 + jg);
            *(float4*)rr[1] = *(const float4*)(W1 + (size_t)(i0 + 1) * 128 + jg);
            *(float4*)rr[2] = *(const float4*)(W1 + (size_t)(i0 + 2) * 128 + jg);
            *(float4*)rr[3] = *(const float4*)(W1 + (size_t)(i0 + 3) * 128 + jg);
            #pragma unroll
            for (int jj = 0; jj < 4; jj++) {
                bf16x4 v;
                v[0] = (short)f2bf(rr[0][jj]); v[1] = (short)f2bf(rr[1][jj]);
                v[2] = (short)f2bf(rr[2][jj]); v[3] = (short)f2bf(rr[3][jj]);
                *(bf16x4*)&W1q[w][jl + jj][i0] = v;
            }
        }
    }
    __syncthreads();   // featb visibility (W1q is same-wave)

    // ---- GEMM + fused h1.W2 epilogue ----
    float s[4] = {0.f, 0.f, 0.f, 0.f};
    #pragma unroll
    for (int ntl = 0; ntl < 2; ntl++) {
        f32x4 acc = {0.f, 0.f, 0.f, 0.f};
        #pragma unroll
        for (int kc = 0; kc < 8; kc++) {
            const bf16x8 af = *(const bf16x8*)&featb[col][kc * 32 + quad * 8];
            const bf16x8 bf = *(const bf16x8*)&W1q[w][ntl * 16 + col][kc * 32 + quad * 8];
            acc = __builtin_amdgcn_mfma_f32_16x16x32_bf16(af, bf, acc, 0, 0, 0);
        }
        const int j = w * 32 + ntl * 16 + col;
        const float b1j = b1[j], w2j = W2[j];
        #pragma unroll
        for (int r = 0; r < 4; r++)
            s[r] = fmaf(fmaxf(acc[r] + b1j, 0.0f), w2j, s[r]);
    }
    #pragma unroll
    for (int r = 0; r < 4; r++) {
        float sr = s[r];
        sr += __shfl_xor(sr, 1, 64);
        sr += __shfl_xor(sr, 2, 64);
        sr += __shfl_xor(sr, 4, 64);
        sr += __shfl_xor(sr, 8, 64);
        if (col == 0) sred[w][quad * 4 + r] = sr;
    }
    __syncthreads();
    if (tid < 16) {
        const float logit = sred[0][tid] + sred[1][tid] + sred[2][tid]
                          + sred[3][tid] + b2[0];
        const int grow = r0 + tid;
        if (grow < NROWS) {
            out[grow] = 1.0f / (1.0f + __expf(-logit));
            out[NROWS + grow] = 1.0f;
        }
    }
}

// ---------------------------------------------------------------------------
extern "C" void kernel_launch(void* const* d_in, const int* in_sizes, int n_in,
                              void* d_out, int out_size, void* d_ws, size_t ws_size,
                              hipStream_t stream)
{
    const int*   idx       = (const int*)d_in[0];
    const int*   flg       = (const int*)d_in[1];
    const float* gaps      = (const float*)d_in[2];
    const float* item_emb  = (const float*)d_in[3];
    const float* ans_emb   = (const float*)d_in[4];
    const float* Wq        = (const float*)d_in[5];
    const float* bq        = (const float*)d_in[6];
    const float* Wk        = (const float*)d_in[7];
    const float* bk        = (const float*)d_in[8];
    const float* Wv        = (const float*)d_in[9];
    const float* bv        = (const float*)d_in[10];
    const float* Wh        = (const float*)d_in[11];
    const float* bh        = (const float*)d_in[12];
    const float* W1        = (const float*)d_in[13];
    const float* b1        = (const float*)d_in[14];
    const float* W2        = (const float*)d_in[15];
    const float* b2        = (const float*)d_in[16];
    const float* theta_raw = (const float*)d_in[17];
    (void)in_sizes; (void)n_in; (void)ws_size;

    const size_t QKV = (size_t)BSZ * HN * SSZ * DN;   // 524288 elements
    unsigned short* Qts = (unsigned short*)d_ws;
    unsigned short* Kts = Qts + QKV;
    unsigned short* Vts = Kts + QKV;
    float* ec  = (float*)(Vts + QKV);
    float* srw = ec + (size_t)BSZ * SSZ * EMBD;
    float* csw = srw + (size_t)BSZ * HN * SSZ;

    float* out = (float*)d_out;

    embed5_kernel<<<BSZ * SSZ / 16, 256, 0, stream>>>(
        idx, flg, item_emb, ans_emb, Wq, bq, Wk, bk, Wv, bv, Wh, bh,
        Qts, Kts, Vts, ec, srw);
    attn5_kernel<<<BSZ * HN * 16, 256, 0, stream>>>(
        Qts, Kts, Vts, srw, gaps, theta_raw, csw);
    mlp4_kernel<<<(NROWS + 15) / 16, 256, 0, stream>>>(
        csw, ec, W1, b1, W2, b2, out);
}